// Round 1
// baseline (188.220 us; speedup 1.0000x reference)
//
#include <hip/hip_runtime.h>

#define BLK 256
#define IPER 4
#define TJ 256

// Monotonic float<->uint mapping so uint atomicMin == float min (handles negatives).
__device__ __forceinline__ unsigned int fmap(float f) {
  unsigned int b = __float_as_uint(f);
  return (b & 0x80000000u) ? ~b : (b | 0x80000000u);
}
__device__ __forceinline__ float funmap(unsigned int u) {
  return __uint_as_float((u & 0x80000000u) ? (u ^ 0x80000000u) : ~u);
}

__global__ void cl_init(unsigned int* __restrict__ u, int n) {
  int i = blockIdx.x * BLK + threadIdx.x;
  if (i < n) u[i] = 0xFFFFFFFFu;  // maps to "+infinity" under fmap ordering
}

// P,Q: [B,3,N] (x at +0, y at +N, z at +2N). For each i in P's slice of this
// block, min over this block's j-slice of (|q_j|^2 - 2 p_i . q_j).
// (|p_i|^2 is added later in cl_reduce -- it doesn't affect the argmin.)
__global__ __launch_bounds__(BLK) void cl_nn(
    const float* __restrict__ P, const float* __restrict__ Q,
    unsigned int* __restrict__ umin, int N, int jslice) {
  __shared__ float4 sq[TJ];
  const int b = blockIdx.z;
  const int t = threadIdx.x;
  const int ibase = blockIdx.x * (BLK * IPER);
  const int jbase = blockIdx.y * jslice;
  const size_t boff = (size_t)b * 3 * N;

  float m0[IPER], m1[IPER], m2[IPER], best[IPER];
#pragma unroll
  for (int k = 0; k < IPER; ++k) {
    int i = ibase + k * BLK + t;
    m0[k] = -2.0f * P[boff + i];
    m1[k] = -2.0f * P[boff + N + i];
    m2[k] = -2.0f * P[boff + 2 * N + i];
    best[k] = 3.0e38f;
  }

  for (int jb = 0; jb < jslice; jb += TJ) {
    int j = jbase + jb + t;
    float qx = Q[boff + j];
    float qy = Q[boff + N + j];
    float qz = Q[boff + 2 * N + j];
    float nq = fmaf(qz, qz, fmaf(qy, qy, qx * qx));
    __syncthreads();  // protect previous tile's readers
    sq[t] = make_float4(qx, qy, qz, nq);
    __syncthreads();
#pragma unroll 4
    for (int jj = 0; jj < TJ; jj += 2) {
      float4 qa = sq[jj];
      float4 qb = sq[jj + 1];
#pragma unroll
      for (int k = 0; k < IPER; ++k) {
        float ta = fmaf(m2[k], qa.z, fmaf(m1[k], qa.y, fmaf(m0[k], qa.x, qa.w)));
        float tb = fmaf(m2[k], qb.z, fmaf(m1[k], qb.y, fmaf(m0[k], qb.x, qb.w)));
        best[k] = fminf(best[k], fminf(ta, tb));  // hope for v_min3_f32
      }
    }
  }
#pragma unroll
  for (int k = 0; k < IPER; ++k) {
    int i = ibase + k * BLK + t;
    atomicMin(&umin[(size_t)b * N + i], fmap(best[k]));
  }
}

// Single block: decode mins, add |p|^2, sum in double, write mean.
__global__ __launch_bounds__(BLK) void cl_reduce(
    const float* __restrict__ in_pc, const float* __restrict__ tgt_pc,
    const unsigned int* __restrict__ u1, const unsigned int* __restrict__ u2,
    float* __restrict__ out, int N, int B) {
  const int t = threadIdx.x;
  double s = 0.0;
  for (int b = 0; b < B; ++b) {
    const size_t boff = (size_t)b * 3 * N;
    for (int i = t; i < N; i += BLK) {
      float x1 = in_pc[boff + i], y1 = in_pc[boff + N + i], z1 = in_pc[boff + 2 * N + i];
      float x2 = tgt_pc[boff + i], y2 = tgt_pc[boff + N + i], z2 = tgt_pc[boff + 2 * N + i];
      float n1 = fmaf(z1, z1, fmaf(y1, y1, x1 * x1));
      float n2 = fmaf(z2, z2, fmaf(y2, y2, x2 * x2));
      float d1 = funmap(u1[(size_t)b * N + i]) + n1;  // dist1[b,i]
      float d2 = funmap(u2[(size_t)b * N + i]) + n2;  // dist2[b,i]
      s += (double)d1 + (double)d2;
    }
  }
  // wave reduce (64 lanes), then cross-wave via LDS
  for (int off = 32; off > 0; off >>= 1) s += __shfl_down(s, off, 64);
  __shared__ double sw[BLK / 64];
  if ((t & 63) == 0) sw[t >> 6] = s;
  __syncthreads();
  if (t == 0) {
    double tot = 0.0;
    for (int w = 0; w < BLK / 64; ++w) tot += sw[w];
    out[0] = (float)(tot / (2.0 * (double)B * (double)N));
  }
}

extern "C" void kernel_launch(void* const* d_in, const int* in_sizes, int n_in,
                              void* d_out, int out_size, void* d_ws, size_t ws_size,
                              hipStream_t stream) {
  const float* in_pc = (const float*)d_in[0];
  const float* tgt_pc = (const float*)d_in[1];
  const int B = 2, N = 16384;
  unsigned int* u1 = (unsigned int*)d_ws;           // B*N uints
  unsigned int* u2 = u1 + (size_t)B * N;            // B*N uints (256 KB total)

  int n_u = 2 * B * N;
  cl_init<<<dim3((n_u + BLK - 1) / BLK), dim3(BLK), 0, stream>>>(u1, n_u);

  const int S = 16;                 // j-slices per direction
  const int jslice = N / S;         // 1024
  dim3 grid(N / (BLK * IPER), S, B);  // (16,16,2) = 512 blocks, 2 waves/SIMD
  cl_nn<<<grid, dim3(BLK), 0, stream>>>(in_pc, tgt_pc, u1, N, jslice);  // dist1 core
  cl_nn<<<grid, dim3(BLK), 0, stream>>>(tgt_pc, in_pc, u2, N, jslice);  // dist2 core

  cl_reduce<<<dim3(1), dim3(BLK), 0, stream>>>(in_pc, tgt_pc, u1, u2,
                                               (float*)d_out, N, B);
}

// Round 2
// 142.483 us; speedup vs baseline: 1.3210x; 1.3210x over previous
//
#include <hip/hip_runtime.h>

#define BLK 256
#define IPER 4
#define TJ 256
#define S_SLICES 16  // j-slices per direction

// Monotonic float<->uint mapping so uint atomicMin == float min (handles negatives).
__device__ __forceinline__ unsigned int fmap(float f) {
  unsigned int b = __float_as_uint(f);
  return (b & 0x80000000u) ? ~b : (b | 0x80000000u);
}
__device__ __forceinline__ float funmap(unsigned int u) {
  return __uint_as_float((u & 0x80000000u) ? (u ^ 0x80000000u) : ~u);
}

__global__ void cl_init(unsigned int* __restrict__ u, int n, float* __restrict__ out) {
  int i = blockIdx.x * BLK + threadIdx.x;
  if (i < n) u[i] = 0xFFFFFFFFu;  // "+inf" under fmap ordering
  if (i == 0) out[0] = 0.0f;      // accumulator for the final mean
}

// Both chamfer directions in one launch. blockIdx.z in [0, 2B):
//   dir = z/B: 0 -> P=in, Q=tgt (dist1);  1 -> P=tgt, Q=in (dist2)
// For each i in P: min over this block's j-slice of (|q_j|^2 - 2 p_i . q_j);
// |p_i|^2 added in cl_reduce (doesn't affect argmin).
__global__ __launch_bounds__(BLK) void cl_nn(
    const float* __restrict__ A, const float* __restrict__ Bp,
    unsigned int* __restrict__ umin, int N, int jslice, int Bn) {
  __shared__ float4 sq[TJ];
  const int z = blockIdx.z;
  const int dir = z / Bn;
  const int b = z - dir * Bn;
  const float* __restrict__ P = dir ? Bp : A;
  const float* __restrict__ Q = dir ? A : Bp;
  unsigned int* __restrict__ um = umin + ((size_t)dir * Bn + b) * N;

  const int t = threadIdx.x;
  const int ibase = blockIdx.x * (BLK * IPER);
  const int jbase = blockIdx.y * jslice;
  const size_t boff = (size_t)b * 3 * N;

  float m0[IPER], m1[IPER], m2[IPER], best[IPER];
#pragma unroll
  for (int k = 0; k < IPER; ++k) {
    int i = ibase + k * BLK + t;
    m0[k] = -2.0f * P[boff + i];
    m1[k] = -2.0f * P[boff + N + i];
    m2[k] = -2.0f * P[boff + 2 * N + i];
    best[k] = 3.0e38f;
  }

  for (int jb = 0; jb < jslice; jb += TJ) {
    int j = jbase + jb + t;
    float qx = Q[boff + j];
    float qy = Q[boff + N + j];
    float qz = Q[boff + 2 * N + j];
    float nq = fmaf(qz, qz, fmaf(qy, qy, qx * qx));
    __syncthreads();  // protect previous tile's readers
    sq[t] = make_float4(qx, qy, qz, nq);
    __syncthreads();
    // Explicit 4-wide j unroll: 4 float4 loads in flight, 16 independent
    // fma chains for latency hiding, min-tree for v_min3 fusion.
    for (int jj = 0; jj < TJ; jj += 4) {
      float4 q0 = sq[jj + 0];
      float4 q1 = sq[jj + 1];
      float4 q2 = sq[jj + 2];
      float4 q3 = sq[jj + 3];
#pragma unroll
      for (int k = 0; k < IPER; ++k) {
        float t0 = fmaf(m2[k], q0.z, fmaf(m1[k], q0.y, fmaf(m0[k], q0.x, q0.w)));
        float t1 = fmaf(m2[k], q1.z, fmaf(m1[k], q1.y, fmaf(m0[k], q1.x, q1.w)));
        float t2 = fmaf(m2[k], q2.z, fmaf(m1[k], q2.y, fmaf(m0[k], q2.x, q2.w)));
        float t3 = fmaf(m2[k], q3.z, fmaf(m1[k], q3.y, fmaf(m0[k], q3.x, q3.w)));
        best[k] = fminf(fminf(best[k], fminf(t0, t1)), fminf(t2, t3));
      }
    }
  }
#pragma unroll
  for (int k = 0; k < IPER; ++k) {
    int i = ibase + k * BLK + t;
    atomicMin(&um[i], fmap(best[k]));
  }
}

// Parallel final reduce: 32 blocks, per-thread double partials over the
// 2*B*N min entries (+|p|^2), block reduce, one scaled float atomicAdd each.
__global__ __launch_bounds__(BLK) void cl_reduce(
    const float* __restrict__ in_pc, const float* __restrict__ tgt_pc,
    const unsigned int* __restrict__ u, float* __restrict__ out, int N, int Bn) {
  const int t = threadIdx.x;
  const int total = 2 * Bn * N;
  const int gid = blockIdx.x * BLK + t;
  const int gstride = gridDim.x * BLK;
  double s = 0.0;
  for (int idx = gid; idx < total; idx += gstride) {
    int dir = idx / (Bn * N);
    int rem = idx - dir * (Bn * N);
    int b = rem / N;
    int i = rem - b * N;
    const float* Pp = dir ? tgt_pc : in_pc;
    size_t boff = (size_t)b * 3 * N;
    float x = Pp[boff + i], y = Pp[boff + N + i], zc = Pp[boff + 2 * N + i];
    float np = fmaf(zc, zc, fmaf(y, y, x * x));
    s += (double)(funmap(u[idx]) + np);
  }
  for (int off = 32; off > 0; off >>= 1) s += __shfl_down(s, off, 64);
  __shared__ double sw[BLK / 64];
  if ((t & 63) == 0) sw[t >> 6] = s;
  __syncthreads();
  if (t == 0) {
    double tot = 0.0;
    for (int w = 0; w < BLK / 64; ++w) tot += sw[w];
    // mean = sum(all d)/(2*B*N); accumulate pre-scaled partials.
    atomicAdd(out, (float)(tot / (2.0 * (double)Bn * (double)N)));
  }
}

extern "C" void kernel_launch(void* const* d_in, const int* in_sizes, int n_in,
                              void* d_out, int out_size, void* d_ws, size_t ws_size,
                              hipStream_t stream) {
  const float* in_pc = (const float*)d_in[0];
  const float* tgt_pc = (const float*)d_in[1];
  const int B = 2, N = 16384;
  unsigned int* u = (unsigned int*)d_ws;  // [2][B][N] uints = 256 KB
  float* out = (float*)d_out;

  int n_u = 2 * B * N;
  cl_init<<<dim3((n_u + BLK - 1) / BLK), dim3(BLK), 0, stream>>>(u, n_u, out);

  const int jslice = N / S_SLICES;                    // 1024
  dim3 grid(N / (BLK * IPER), S_SLICES, 2 * B);       // (16,16,4) = 1024 blocks
  cl_nn<<<grid, dim3(BLK), 0, stream>>>(in_pc, tgt_pc, u, N, jslice, B);

  cl_reduce<<<dim3(32), dim3(BLK), 0, stream>>>(in_pc, tgt_pc, u, out, N, B);
}